// Round 1
// baseline (15160.039 us; speedup 1.0000x reference)
//
#include <hip/hip_runtime.h>

#define NCOMP    8
#define CIN      512
#define COUT     256
#define CIN_SUB  64
#define COUT_SUB 32
#define H        64
#define OHW      128
#define KK       4
#define NB       8

// Cayley-Dickson component-index table |comp| for n=8, expanded by hand from
// the reference's get_comp_mat(8). sign(i,j) = +1 iff i >= j.
__device__ const int d_idx8[8][8] = {
    {0,1,2,1,4,3,2,3},
    {1,0,3,2,5,4,1,2},
    {2,1,0,1,6,5,4,3},
    {3,2,1,0,7,6,5,4},
    {4,3,2,3,0,1,2,1},
    {5,4,1,2,1,0,3,2},
    {6,5,4,3,2,1,0,1},
    {7,6,5,4,3,2,1,0}};

// Build Wt[kh][kw][icin][oc]  (4*4*512*256 floats = 8 MB) and fused bias bbig[256].
// Wt[kh][kw][j*64+ci][i*32+co] = sign(i,j) * W[idx8[i][j]][ci][co][kh][kw]
__global__ void prep_weights(const float* __restrict__ W, const float* __restrict__ bias,
                             float* __restrict__ Wt, float* __restrict__ bbig) {
    int t = blockIdx.x * blockDim.x + threadIdx.x;
    if (t < KK * KK * CIN * COUT) {
        int oc   = t & (COUT - 1);
        int icin = (t >> 8) & (CIN - 1);
        int kw   = (t >> 17) & 3;
        int kh   = t >> 19;
        int i = oc >> 5, co = oc & 31;
        int j = icin >> 6, ci = icin & 63;
        int m = d_idx8[i][j];
        float s = (i >= j) ? 1.0f : -1.0f;
        Wt[t] = s * W[(((m * CIN_SUB + ci) * COUT_SUB + co) * KK + kh) * KK + kw];
    }
    if (t < COUT) {
        int i = t >> 5, co = t & 31;
        float acc = 0.0f;
        for (int j = 0; j < NCOMP; ++j) {
            float s = (i >= j) ? 1.0f : -1.0f;
            acc += s * bias[d_idx8[i][j] * COUT_SUB + co];
        }
        bbig[t] = acc;
    }
}

// Direct transpose-conv: thread = (b, oh, ow, 8 consecutive oc).
// out[b,oc,oh,ow] = bbig[oc] + sum_{valid kh,kw} sum_ic Wt[kh][kw][ic][oc] * x[b,ic,ih,iw]
// with oh = 2*ih - 1 + kh  (parity: exactly 2 kh and 2 kw candidates).
__launch_bounds__(128)
__global__ void htconv_main(const float* __restrict__ x, const float* __restrict__ Wt,
                            const float* __restrict__ bbig, float* __restrict__ out) {
    const int ow  = threadIdx.x;   // 0..127
    const int oh  = blockIdx.x;    // 0..127
    const int ocg = blockIdx.y;    // 0..31
    const int b   = blockIdx.z;    // 0..7
    const int oc0 = ocg * 8;

    const int kh0 = (oh + 1) & 1;
    const int kw0 = (ow + 1) & 1;

    float acc[8];
#pragma unroll
    for (int k = 0; k < 8; ++k) acc[k] = bbig[oc0 + k];

    const float* xb = x + (size_t)b * CIN * H * H;

#pragma unroll
    for (int th = 0; th < 2; ++th) {
        const int kh = kh0 + 2 * th;
        const int ih = (oh + 1 - kh) >> 1;   // even numerator by parity
        if (ih < 0 || ih >= H) continue;
#pragma unroll
        for (int tw = 0; tw < 2; ++tw) {
            const int kw = kw0 + 2 * tw;
            const int iw = (ow + 1 - kw) >> 1;
            if (iw < 0 || iw >= H) continue;
            const float* xp = xb + ih * H + iw;
            const float4* wp = (const float4*)(Wt + (size_t)((kh * KK + kw) * CIN) * COUT + oc0);
#pragma unroll 4
            for (int c = 0; c < CIN; ++c) {
                const float xv = xp[c * (H * H)];
                const float4 w0 = wp[c * (COUT / 4)];
                const float4 w1 = wp[c * (COUT / 4) + 1];
                acc[0] += xv * w0.x; acc[1] += xv * w0.y;
                acc[2] += xv * w0.z; acc[3] += xv * w0.w;
                acc[4] += xv * w1.x; acc[5] += xv * w1.y;
                acc[6] += xv * w1.z; acc[7] += xv * w1.w;
            }
        }
    }

    float* op = out + (((size_t)b * COUT + oc0) * OHW + oh) * OHW + ow;
#pragma unroll
    for (int k = 0; k < 8; ++k) op[(size_t)k * OHW * OHW] = acc[k];
}

extern "C" void kernel_launch(void* const* d_in, const int* in_sizes, int n_in,
                              void* d_out, int out_size, void* d_ws, size_t ws_size,
                              hipStream_t stream) {
    const float* x    = (const float*)d_in[0];  // [8,512,64,64]
    const float* W    = (const float*)d_in[1];  // [8,64,32,4,4]
    const float* bias = (const float*)d_in[2];  // [8,32]
    float* out  = (float*)d_out;                // [8,256,128,128]
    float* Wt   = (float*)d_ws;                 // 4*4*512*256 floats = 8 MB
    float* bbig = Wt + KK * KK * CIN * COUT;    // 256 floats

    const int prep_n = KK * KK * CIN * COUT;    // 2,097,152
    prep_weights<<<(prep_n + 255) / 256, 256, 0, stream>>>(W, bias, Wt, bbig);
    htconv_main<<<dim3(OHW, COUT / 8, NB), dim3(OHW), 0, stream>>>(x, Wt, bbig, out);
}

// Round 2
// 372.228 us; speedup vs baseline: 40.7279x; 40.7279x over previous
//
#include <hip/hip_runtime.h>
#include <hip/hip_bf16.h>

typedef unsigned short ushort_t;
typedef __attribute__((ext_vector_type(8))) short short8;
typedef __attribute__((ext_vector_type(4))) float f32x4;

#define NCOMP    8
#define CIN      512
#define COUT     256
#define H        64
#define HP       66      // padded spatial dim (halo 1 each side)
#define OHW      128
#define NB       8

// Cayley-Dickson |comp| table for n=8 (verified in round 1); sign(i,j)=+1 iff i>=j.
__device__ const int d_idx8[8][8] = {
    {0,1,2,1,4,3,2,3},
    {1,0,3,2,5,4,1,2},
    {2,1,0,1,6,5,4,3},
    {3,2,1,0,7,6,5,4},
    {4,3,2,3,0,1,2,1},
    {5,4,1,2,1,0,3,2},
    {6,5,4,3,2,1,0,1},
    {7,6,5,4,3,2,1,0}};

// Tap tables (verified by round-1 kernel's parity math):
// output parity p, tap index a: kernel index kh and input offset dh (ih = ohh + dh).
__device__ const int kh_tab[2][2] = {{1,3},{0,2}};
__device__ const int dh_tab[2][2] = {{0,-1},{1,0}};

// ---------------- prep: x -> padded, transposed, bf16 ----------------
// xpadT[b][ih+1][iw+1][ic]  (bf16, halo rows/cols pre-zeroed by memset)
__global__ void prep_x(const float* __restrict__ x, ushort_t* __restrict__ xpadT) {
    __shared__ ushort_t tile[32][33];
    const int ih  = blockIdx.x;          // 0..63
    const int iw0 = (blockIdx.y & 1) * 32;
    const int ic0 = (blockIdx.y >> 1) * 32;
    const int b   = blockIdx.z;
    const int t   = threadIdx.x;         // 0..255

    for (int e = t; e < 1024; e += 256) {
        int icl = e >> 5, iwl = e & 31;
        float v = x[(((size_t)b * CIN + ic0 + icl) * H + ih) * H + iw0 + iwl];
        __hip_bfloat16 h = __float2bfloat16(v);
        tile[icl][iwl] = *(ushort_t*)&h;
    }
    __syncthreads();
    const int iwl = t >> 3, g = t & 7;   // 32 iw x 8 groups of 4 ic
    ushort4 v;
    v.x = tile[g * 4 + 0][iwl];
    v.y = tile[g * 4 + 1][iwl];
    v.z = tile[g * 4 + 2][iwl];
    v.w = tile[g * 4 + 3][iwl];
    ushort_t* dst = xpadT + (((size_t)b * HP + ih + 1) * HP + iw0 + iwl + 1) * CIN + ic0 + g * 4;
    *(ushort4*)dst = v;
}

// ---------------- prep: fused bf16 weights + bias ----------------
// Abf layout [cls][ks(64)][oc(256)][kin(32)] so each K-step's A-tile is a
// contiguous 8KB block (global_load_lds-friendly).
__global__ void prep_w(const float* __restrict__ W, const float* __restrict__ bias,
                       ushort_t* __restrict__ Abf, float* __restrict__ bbig) {
    const int t = blockIdx.x * blockDim.x + threadIdx.x;
    if (t < 4 * 64 * 256 * 32) {
        int kin = t & 31;
        int oc  = (t >> 5) & 255;
        int ks  = (t >> 13) & 63;
        int cls = t >> 19;
        int k  = ks * 32 + kin;
        int a  = k >> 10, c = (k >> 9) & 1, ic = k & 511;
        int ph = cls >> 1, pw = cls & 1;
        int kh = kh_tab[ph][a], kw = kh_tab[pw][c];
        int i = oc >> 5, co = oc & 31;
        int j = ic >> 6, ci = ic & 63;
        float s = (i >= j) ? 1.0f : -1.0f;
        float v = s * W[(((size_t)(d_idx8[i][j] * 64 + ci) * 32 + co) * 4 + kh) * 4 + kw];
        __hip_bfloat16 h = __float2bfloat16(v);
        Abf[t] = *(ushort_t*)&h;
    }
    if (t < COUT) {
        int i = t >> 5, co = t & 31;
        float acc = 0.0f;
        for (int j = 0; j < NCOMP; ++j)
            acc += ((i >= j) ? 1.0f : -1.0f) * bias[d_idx8[i][j] * 32 + co];
        bbig[t] = acc;
    }
}

// ---------------- main: implicit-GEMM MFMA ----------------
__device__ __forceinline__ void async16(void* lds_dst, const void* g_src) {
    __builtin_amdgcn_global_load_lds(
        (const __attribute__((address_space(1))) unsigned int*)g_src,
        (__attribute__((address_space(3))) unsigned int*)lds_dst,
        16, 0, 0);
}

__launch_bounds__(256)
__global__ void htconv_mfma(const ushort_t* __restrict__ xpadT,
                            const ushort_t* __restrict__ Abf,
                            const float* __restrict__ bbig,
                            float* __restrict__ out) {
    // A: 128x32 bf16 (8KB) | B: 128x32 bf16 (8KB); k-chunk XOR-swizzled by (row>>1)&3
    __shared__ __align__(16) ushort_t smem[8192];
    char* sb = (char*)smem;

    const int t     = threadIdx.x;            // 0..255
    const int ntile = blockIdx.x;             // 0..31 -> ohh0 = 2*ntile
    const int mtile = blockIdx.y;             // 0..1
    const int cls   = blockIdx.z & 3;
    const int b     = blockIdx.z >> 2;
    const int ph = cls >> 1, pw = cls & 1;
    const int ohh0 = ntile * 2;

    // ---- staging addresses ----
    const int srcc = (((t & 3) ^ ((t >> 3) & 3)) * 8);  // swizzled k-chunk (elements)
    const int m_a  = t >> 2;                            // row 0..63 within half-tile
    const ushort_t* ap = Abf + (((size_t)cls * 64) * 256 + (size_t)mtile * 128 + m_a) * 32 + srcc;

    const int dh0 = dh_tab[ph][0], dh1 = dh_tab[ph][1];
    const int dw0 = dh_tab[pw][0], dw1 = dh_tab[pw][1];
    const int oww = t >> 2;                             // pixel col 0..63
    const ushort_t* bp[2][2][2];
#pragma unroll
    for (int a = 0; a < 2; ++a) {
        int dh = (a == 0) ? dh0 : dh1;
#pragma unroll
        for (int c = 0; c < 2; ++c) {
            int dw = (c == 0) ? dw0 : dw1;
#pragma unroll
            for (int row = 0; row < 2; ++row) {
                size_t idx = (((size_t)b * HP + ohh0 + row + dh + 1) * HP + oww + dw + 1) * CIN + srcc;
                bp[a][c][row] = xpadT + idx;
            }
        }
    }

    // ---- fragment read offsets ----
    const int lane = t & 63, wave = t >> 6;
    const int wm = wave >> 1, wn = wave & 1;
    const int col = lane & 15, quad = lane >> 4;
    const int soff = (quad ^ ((col >> 1) & 3)) * 16;    // bytes
    const int aoff = (wm * 64 + col) * 64 + soff;       // bytes into A region
    const int boff = 8192 + (wn * 64 + col) * 64 + soff;

    f32x4 acc[4][4];
#pragma unroll
    for (int i = 0; i < 4; ++i)
#pragma unroll
        for (int j = 0; j < 4; ++j)
            acc[i][j] = (f32x4){0.f, 0.f, 0.f, 0.f};

    // ---- K loop: (a, c) taps outer, 16 ic-chunks inner ----
#pragma unroll
    for (int a = 0; a < 2; ++a) {
#pragma unroll
        for (int c = 0; c < 2; ++c) {
            const ushort_t* b0 = bp[a][c][0];
            const ushort_t* b1 = bp[a][c][1];
            for (int kk = 0; kk < 16; ++kk) {
                async16(sb + t * 16,         ap);
                async16(sb + 4096 + t * 16,  ap + 2048);
                async16(sb + 8192 + t * 16,  b0);
                async16(sb + 12288 + t * 16, b1);
                ap += 8192; b0 += 32; b1 += 32;
                __syncthreads();

                short8 af[4], bf[4];
#pragma unroll
                for (int s = 0; s < 4; ++s) {
                    af[s] = *(const short8*)(sb + aoff + s * 1024);
                    bf[s] = *(const short8*)(sb + boff + s * 1024);
                }
#pragma unroll
                for (int sm = 0; sm < 4; ++sm)
#pragma unroll
                    for (int sn = 0; sn < 4; ++sn)
                        acc[sm][sn] = __builtin_amdgcn_mfma_f32_16x16x32_bf16(
                            af[sm], bf[sn], acc[sm][sn], 0, 0, 0);
                __syncthreads();
            }
        }
    }

    // ---- epilogue: bias + stride-2 scatter store ----
    const int oh = 2 * (ohh0 + wn) + ph;
#pragma unroll
    for (int sm = 0; sm < 4; ++sm) {
#pragma unroll
        for (int r = 0; r < 4; ++r) {
            const int occ = mtile * 128 + wm * 64 + sm * 16 + quad * 4 + r;
            const float bv = bbig[occ];
            float* obase = out + (((size_t)b * COUT + occ) * OHW + oh) * OHW + pw;
#pragma unroll
            for (int sn = 0; sn < 4; ++sn) {
                const int owi = sn * 16 + col;          // pixel col 0..63
                obase[2 * owi] = acc[sm][sn][r] + bv;
            }
        }
    }
}

extern "C" void kernel_launch(void* const* d_in, const int* in_sizes, int n_in,
                              void* d_out, int out_size, void* d_ws, size_t ws_size,
                              hipStream_t stream) {
    const float* x    = (const float*)d_in[0];  // [8,512,64,64]
    const float* W    = (const float*)d_in[1];  // [8,64,32,4,4]
    const float* bias = (const float*)d_in[2];  // [8,32]
    float* out = (float*)d_out;                 // [8,256,128,128]

    ushort_t* xpadT = (ushort_t*)d_ws;                       // 8*66*66*512 = 17,842,176 elems
    ushort_t* Abf   = xpadT + (size_t)NB * HP * HP * CIN;    // 4*64*256*32 = 2,097,152 elems
    float*    bbig  = (float*)(Abf + (size_t)4 * 64 * 256 * 32);

    hipMemsetAsync(xpadT, 0, (size_t)NB * HP * HP * CIN * sizeof(ushort_t), stream);
    prep_x<<<dim3(H, 32, NB), 256, 0, stream>>>(x, xpadT);
    prep_w<<<dim3((4 * 64 * 256 * 32) / 256), 256, 0, stream>>>(W, bias, Abf, bbig);
    htconv_mfma<<<dim3(32, 2, 32), 256, 0, stream>>>(xpadT, Abf, bbig, out);
}